// Round 1
// 358.980 us; speedup vs baseline: 1.0012x; 1.0012x over previous
//
#include <hip/hip_runtime.h>

// CASSI forward: y[m, n+l] += x[m,n,l] * ca[m,n]
// x: (1, M, N, L) fp32, ca: (1, M, N, 1) fp32, y: (1, M, N+L-1, 1) fp32
//
// R5: EXCLUSIVE-WRITE restructure. rocprof showed dur_us (359) is dominated
// by 1-GiB fillBufferAligned dispatches (~160 us each) — output-arena
// reset/re-poison work tied to this kernel's RMW-on-d_out semantics (memset +
// atomicAdd). The scatter kernel itself is <158 us (absent from top-5) and
// roofline says ~42 us for the 272 MB it must stream.
//
// New structure: one block per row m (grid=1024 = exactly 4 blocks/CU x 256
// CUs = 32 waves/CU, zero tail). Each block loops over the row's 8 chunks of
// 128 columns with the proven stage->gather pipeline. The 63-column seam
// between adjacent chunks is carried in a tiny LDS ping-pong buffer: chunk
// c's tail partial sums (output cols [n0+128, n0+190]) become chunk c+1's
// head carry. Every one of the 1087 output columns per row is written
// EXACTLY ONCE with a plain store: no hipMemsetAsync, no atomics, no
// dependence on prior d_out contents.

#define CASSI_M 1024
#define CASSI_N 1024
#define CASSI_L 64
#define CASSI_OUTW (CASSI_N + CASSI_L - 1)  // 1087

constexpr int CN = 128;               // n-columns per chunk
constexpr int P = CASSI_L + 1;        // 65: padded LDS stride (stride%32==1 -> 2-way max, free)
constexpr int NCHUNK = CASSI_N / CN;  // 8
constexpr int BLK = 512;              // 8 waves/block; 4 blocks/CU = 32 waves/CU (LDS-limited: 4*33.8KB=135KB)
constexpr int SPC = (CN * CASSI_L) / (BLK * 4);  // 4 float4 per thread per chunk
constexpr int OWIN = CN + CASSI_L - 1;           // 191 partial outputs per chunk

__global__ __launch_bounds__(BLK) void cassi_row_kernel(
    const float* __restrict__ x, const float* __restrict__ ca,
    float* __restrict__ out) {
    __shared__ float xs[CN * P];          // 33,280 B
    __shared__ float carry[2][CASSI_L];   // ping-pong seam carry (63 live/buf)

    const int m = blockIdx.x;  // one block owns one spatial row
    const int t = threadIdx.x;

    // zero both carry buffers; ordered before first gather by the stage barrier
    if (t < CASSI_L) {
        carry[0][t] = 0.0f;
        carry[1][t] = 0.0f;
    }

    const float* __restrict__ xrow = x + (size_t)m * CASSI_N * CASSI_L;
    const float* __restrict__ crow = ca + (size_t)m * CASSI_N;
    float* __restrict__ orow = out + (size_t)m * CASSI_OUTW;

    for (int c = 0; c < NCHUNK; ++c) {
        const int n0 = c * CN;
        const float* __restrict__ xsrc = xrow + (size_t)n0 * CASSI_L;
        const float* __restrict__ csrc = crow + n0;

        // ---- stage chunk into LDS, ca folded (coalesced float4 burst) ----
#pragma unroll
        for (int s = 0; s < SPC; ++s) {
            const int f = (s * BLK + t) * 4;  // [0, 8192)
            const int nrel = f >> 6;
            const int l = f & 63;
            const float4 v = *reinterpret_cast<const float4*>(xsrc + f);
            const float cv = csrc[nrel];
            float* dst = &xs[nrel * P + l];
            dst[0] = v.x * cv;
            dst[1] = v.y * cv;
            dst[2] = v.z * cv;
            dst[3] = v.w * cv;
        }
        __syncthreads();

        // ---- gather: thread t owns output column o = n0 + t, t < 191 ----
        if (t < OWIN) {
            const int k = t;
            float s0 = 0.0f, s1 = 0.0f;
#pragma unroll
            for (int l = 0; l < CASSI_L; l += 2) {
                const int n_a = k - l;
                const int n_b = k - l - 1;
                // wrapped address always in-bounds; invalid lanes masked to 0
                const float va = xs[(n_a & (CN - 1)) * P + l];
                const float vb = xs[(n_b & (CN - 1)) * P + l + 1];
                s0 += ((unsigned)n_a < (unsigned)CN) ? va : 0.0f;
                s1 += ((unsigned)n_b < (unsigned)CN) ? vb : 0.0f;
            }
            const float s = s0 + s1;
            const int cur = c & 1;
            if (k < CASSI_L - 1) {
                // head columns [n0, n0+62]: complete with previous chunk's carry
                orow[n0 + k] = s + carry[cur][k];
            } else if (k < CN) {
                // interior columns [n0+63, n0+127]: fully local to this chunk
                orow[n0 + k] = s;
            } else if (c == NCHUNK - 1) {
                // dispersion tail [1024, 1086]: fully local to the last chunk
                orow[n0 + k] = s;
            } else {
                // seam columns [n0+128, n0+190]: park as carry for chunk c+1
                carry[cur ^ 1][k - CN] = s;
            }
        }
        // protect xs reuse next chunk; also orders carry write -> carry read
        __syncthreads();
    }
}

extern "C" void kernel_launch(void* const* d_in, const int* in_sizes, int n_in,
                              void* d_out, int out_size, void* d_ws, size_t ws_size,
                              hipStream_t stream) {
    const float* x  = (const float*)d_in[0];   // (1, M, N, L)
    const float* ca = (const float*)d_in[1];   // (1, M, N, 1)
    float* out = (float*)d_out;                // (1, M, N+L-1, 1)
    (void)in_sizes; (void)n_in; (void)d_ws; (void)ws_size; (void)out_size;

    // No memset: every output element is written exactly once by the kernel.
    cassi_row_kernel<<<CASSI_M, BLK, 0, stream>>>(x, ca, out);
}